// Round 1
// baseline (313.459 us; speedup 1.0000x reference)
//
#include <hip/hip_runtime.h>
#include <math.h>

// TIME_WARPING: not-a-knot cubic spline fit + warped resample, fused.
//
// Key math: the spline second-derivative system A M = rhs with A = tridiag(1,4,1)
// + not-a-knot corner rows reduces to:
//   M1 = y0 - 2 y1 + y2            (exact)
//   M_{S-2} = y_{S-3} - 2 y_{S-2} + y_{S-1}   (exact)
//   M0 = 2 M1 - M2,  M_{S-1} = 2 M_{S-2} - M_{S-3}
//   interior: Toeplitz (1,4,1) solve with ghost conditions u_1 = u_{S-2} = 0.
// Toeplitz inverse is a convolution with G(k) = (-1)^k r^|k| / (2*sqrt(3)),
// r = 2 - sqrt(3) ~ 0.268; truncated at W=16 (error ~1e-8). Boundary images:
//   M_i = v_i + (-1)^i * ( v1 * r^(i-1) - vS2 * r^(S-2-i) )
// where v1/vS2 are the (zero-padded) convolution evaluated at the ghost points.

#define SLEN 4096
#define WRAD 16            // convolution half-width
#define BLK  256
#define PER  (SLEN / BLK)  // 16 elements per thread

__global__ __launch_bounds__(BLK) void time_warp_kernel(
    const float* __restrict__ x,
    const float* __restrict__ scale,
    const int*   __restrict__ apply_mask,
    float* __restrict__ out,
    int C)
{
    __shared__ float sy[SLEN];             // input signal
    __shared__ float sf[SLEN + 2 * WRAD];  // padded rhs f, later reused for M

    const int bid = blockIdx.x;        // = b*C + c
    const int b   = bid / C;
    const int t   = threadIdx.x;
    const float* __restrict__ xin = x   + (size_t)bid * SLEN;
    float*       __restrict__ o   = out + (size_t)bid * SLEN;

    // Per-sample apply decision (block-uniform branch; safe before barriers).
    if (apply_mask[b] == 0) {
        const float4* __restrict__ xi4 = (const float4*)xin;
        float4*       __restrict__ o4  = (float4*)o;
        #pragma unroll
        for (int s = 0; s < PER / 4; ++s)
            o4[t + BLK * s] = xi4[t + BLK * s];
        return;
    }

    // ---- stage y into LDS (coalesced float4) ----
    {
        const float4* __restrict__ xi4 = (const float4*)xin;
        #pragma unroll
        for (int s = 0; s < PER / 4; ++s)
            ((float4*)sy)[t + BLK * s] = xi4[t + BLK * s];
    }
    // zero pad slots + ghost f slots: sf indices [0, WRAD+1] and [WRAD+SLEN-2, SLEN+2*WRAD-1]
    if (t < WRAD + 2)                 sf[t] = 0.0f;
    if (t >= 32 && t < 32 + WRAD + 2) sf[(SLEN + 2 * WRAD - 1) - (t - 32)] = 0.0f;
    __syncthreads();

    const float M1  = sy[0]        - 2.0f * sy[1]        + sy[2];
    const float MS2 = sy[SLEN - 3] - 2.0f * sy[SLEN - 2] + sy[SLEN - 1];

    // ---- rhs / f into padded LDS ----
    #pragma unroll
    for (int s = 0; s < PER; ++s) {
        int j = t + BLK * s;
        if (j >= 2 && j <= SLEN - 3) {
            float v = 6.0f * (sy[j - 1] - 2.0f * sy[j] + sy[j + 1]);
            if (j == 2)        v -= M1;
            if (j == SLEN - 3) v -= MS2;
            sf[WRAD + j] = v;
        }
    }
    __syncthreads();

    // Green's function taps
    const float r = 0.26794919243112270f;  // 2 - sqrt(3)
    float G[WRAD + 1];
    G[0] = 0.28867513459481287f;           // 1 / (2*sqrt(3))
    #pragma unroll
    for (int k = 1; k <= WRAD; ++k) G[k] = -G[k - 1] * r;

    // ghost-point values of the infinite-convolution solution
    float v1 = 0.0f, vS2 = 0.0f;
    #pragma unroll
    for (int k = 1; k <= WRAD; ++k) {
        v1  += G[k] * sf[WRAD + 1 + k];
        vS2 += G[k] * sf[WRAD + (SLEN - 2) - k];
    }

    const float log2r = -1.8999686269529532f;  // log2(2 - sqrt(3))

    auto conv_at = [&](int i) -> float {
        float acc = G[0] * sf[WRAD + i];
        #pragma unroll
        for (int k = 1; k <= WRAD; ++k)
            acc += G[k] * (sf[WRAD + i - k] + sf[WRAD + i + k]);
        // boundary image corrections (underflow to 0 deep in the interior)
        float corr = v1  * exp2f((float)(i - 1)        * log2r)
                   - vS2 * exp2f((float)(SLEN - 2 - i) * log2r);
        if (i & 1) corr = -corr;
        return acc + corr;
    };

    // ---- compute M into registers, then overwrite sf with M ----
    float mv[PER];
    #pragma unroll
    for (int s = 0; s < PER; ++s) {
        int i = t + BLK * s;
        float m;
        if (i >= 2 && i <= SLEN - 3)  m = conv_at(i);
        else if (i == 1)              m = M1;
        else if (i == SLEN - 2)       m = MS2;
        else if (i == 0)              m = 2.0f * M1  - conv_at(2);
        else                          m = 2.0f * MS2 - conv_at(SLEN - 3);  // i == SLEN-1
        mv[s] = m;
    }
    __syncthreads();
    #pragma unroll
    for (int s = 0; s < PER; ++s)
        sf[WRAD + t + BLK * s] = mv[s];
    __syncthreads();

    // ---- warped evaluation ----
    const float sc = scale[b];
    #pragma unroll
    for (int s = 0; s < PER; ++s) {
        int j = t + BLK * s;
        float w = (float)j * sc;
        if (w > (float)(SLEN - 1)) w = (float)(SLEN - 1);
        int idx = (int)w;
        if (idx > SLEN - 2) idx = SLEN - 2;
        float tt  = w - (float)idx;
        float y0  = sy[idx];
        float y1  = sy[idx + 1];
        float m0  = sf[WRAD + idx];
        float m1v = sf[WRAD + idx + 1];
        float bb = (y1 - y0) - (2.0f * m0 + m1v) * (1.0f / 6.0f);
        float cc = 0.5f * m0;
        float dd = (m1v - m0) * (1.0f / 6.0f);
        o[j] = y0 + tt * (bb + tt * (cc + tt * dd));
    }
}

extern "C" void kernel_launch(void* const* d_in, const int* in_sizes, int n_in,
                              void* d_out, int out_size, void* d_ws, size_t ws_size,
                              hipStream_t stream) {
    const float* x     = (const float*)d_in[0];
    const float* scale = (const float*)d_in[1];
    const int*   mask  = (const int*)d_in[2];
    float*       out   = (float*)d_out;

    const int B     = in_sizes[1];            // 128
    const int total = in_sizes[0];            // B*C*S
    const int C     = total / (B * SLEN);     // 64
    const int nblk  = B * C;                  // 8192

    time_warp_kernel<<<nblk, BLK, 0, stream>>>(x, scale, mask, out, C);
}

// Round 2
// 230.493 us; speedup vs baseline: 1.3599x; 1.3599x over previous
//
#include <hip/hip_runtime.h>
#include <math.h>

// TIME_WARPING: not-a-knot cubic spline fit + warped resample, fused.
//
// Math: spline system A M = rhs, A = tridiag(1,4,1) + not-a-knot corner rows:
//   M1 = y0 - 2 y1 + y2 (exact);  M_{S-2} = y_{S-3} - 2 y_{S-2} + y_{S-1} (exact)
//   M0 = 2 M1 - M2;  M_{S-1} = 2 M_{S-2} - M_{S-3}
//   interior: Toeplitz(1,4,1) with ghost conditions u_1 = u_{S-2} = 0.
// Toeplitz inverse = convolution with G(k) = (-1)^k r^|k| / (2 sqrt(3)),
// r = 2 - sqrt(3); truncated at W=8 (error ~3e-4 vs 0.108 threshold).
// Boundary images: M_i += (-1)^i [ v1 r^(i-1) - vS2 r^(S-2-i) ], v1/vS2 =
// ghost-point values of the zero-padded convolution.
//
// Layout: thread t owns 4 consecutive elements per group, j0 = 4*t + 1024*s,
// s = 0..3 -> all LDS windows are 16B aligned -> ds_read_b128 / ds_write_b128.

#define SLEN 4096
#define WRAD 8
#define BLK  256
#define NG   4   // groups of 4 elements per thread (4*4*256 = 4096)

__global__ __launch_bounds__(BLK, 3) void time_warp_kernel(
    const float* __restrict__ x,
    const float* __restrict__ scale,
    const int*   __restrict__ apply_mask,
    float* __restrict__ out,
    int C)
{
    __shared__ float sy[SLEN];             // input signal
    __shared__ float sf[SLEN + 2 * WRAD];  // padded rhs f
    __shared__ float sm[SLEN];             // second derivatives M

    const int bid = blockIdx.x;   // = b*C + c
    const int b   = bid / C;
    const int t   = threadIdx.x;
    const float* __restrict__ xin = x   + (size_t)bid * SLEN;
    float*       __restrict__ o   = out + (size_t)bid * SLEN;

    // Per-sample apply decision (block-uniform branch before any barrier).
    if (apply_mask[b] == 0) {
        const float4* __restrict__ xi4 = (const float4*)xin;
        float4*       __restrict__ o4  = (float4*)o;
        #pragma unroll
        for (int s = 0; s < NG; ++s)
            o4[t + BLK * s] = xi4[t + BLK * s];
        return;
    }

    // ---- stage y into LDS (coalesced float4 -> ds_write_b128) ----
    {
        const float4* __restrict__ xi4 = (const float4*)xin;
        #pragma unroll
        for (int s = 0; s < NG; ++s)
            *(float4*)&sy[4 * t + 1024 * s] = xi4[t + BLK * s];
    }
    // zero the pure pad slots of sf (interior f slots are written in pass B)
    if (t < WRAD)                      sf[t] = 0.0f;
    else if (t >= 16 && t < 16 + WRAD) sf[(SLEN + 2 * WRAD - 1) - (t - 16)] = 0.0f;
    __syncthreads();

    const float M1  = sy[0]        - 2.0f * sy[1]        + sy[2];
    const float MS2 = sy[SLEN - 3] - 2.0f * sy[SLEN - 2] + sy[SLEN - 1];

    // ---- pass B: rhs f into padded LDS (vectorized windows) ----
    #pragma unroll
    for (int s = 0; s < NG; ++s) {
        const int j0 = 4 * t + 1024 * s;
        float4 yc = *(const float4*)&sy[j0];
        float  ym = (j0 > 0)        ? sy[j0 - 1] : 0.0f;
        float  yp = (j0 + 4 < SLEN) ? sy[j0 + 4] : 0.0f;
        float yv[6] = {ym, yc.x, yc.y, yc.z, yc.w, yp};
        float fe[4];
        #pragma unroll
        for (int e = 0; e < 4; ++e) {
            const int j = j0 + e;
            float v = 6.0f * (yv[e] - 2.0f * yv[e + 1] + yv[e + 2]);
            if (j < 2 || j > SLEN - 3) v = 0.0f;
            if (j == 2)        v -= M1;
            if (j == SLEN - 3) v -= MS2;
            fe[e] = v;
        }
        *(float4*)&sf[WRAD + j0] = make_float4(fe[0], fe[1], fe[2], fe[3]);
    }
    __syncthreads();

    // Green's taps (compile-time folded)
    const float r = 0.26794919243112270f;  // 2 - sqrt(3)
    float G[WRAD + 1];
    G[0] = 0.28867513459481287f;           // 1 / (2 sqrt(3))
    #pragma unroll
    for (int k = 1; k <= WRAD; ++k) G[k] = -G[k - 1] * r;
    const float log2r = -1.8999686269529532f;  // log2(2 - sqrt(3))

    // ghost-point values (broadcast LDS reads, all lanes same address)
    float v1 = 0.0f, vS2 = 0.0f;
    #pragma unroll
    for (int k = 1; k <= WRAD; ++k) {
        v1  += G[k] * sf[WRAD + 1 + k];
        vS2 += G[k] * sf[WRAD + (SLEN - 2) - k];
    }

    // ---- pass C: convolution -> M, vectorized 20-float windows ----
    #pragma unroll
    for (int s = 0; s < NG; ++s) {
        const int j0 = 4 * t + 1024 * s;
        float fw[4 * (WRAD / 4) * 2 + 4];  // 20 floats: f[j0-8 .. j0+11]
        #pragma unroll
        for (int m = 0; m < 5; ++m)
            *(float4*)&fw[4 * m] = *(const float4*)&sf[j0 + 4 * m];  // sf[WRAD + j0-8 + 4m]
        float mv[4];
        #pragma unroll
        for (int e = 0; e < 4; ++e) {
            float acc = G[0] * fw[WRAD + e];
            #pragma unroll
            for (int k = 1; k <= WRAD; ++k)
                acc += G[k] * (fw[WRAD + e - k] + fw[WRAD + e + k]);
            const int i = j0 + e;
            // boundary image corrections (nonzero only near the edges)
            if (i >= 2 && i <= 34) {
                float cc = v1 * exp2f((float)(i - 1) * log2r);
                acc += (i & 1) ? -cc : cc;
            }
            if (i >= SLEN - 36 && i <= SLEN - 3) {
                float cc = vS2 * exp2f((float)(SLEN - 2 - i) * log2r);
                acc += (i & 1) ? cc : -cc;
            }
            mv[e] = acc;
        }
        if (j0 == 0)        { mv[1] = M1;  mv[0] = 2.0f * M1  - mv[2]; }
        if (j0 == SLEN - 4) { mv[2] = MS2; mv[3] = 2.0f * MS2 - mv[1]; }
        *(float4*)&sm[j0] = make_float4(mv[0], mv[1], mv[2], mv[3]);
    }
    __syncthreads();

    // ---- pass D: warped evaluation ----
    const float sc = scale[b];
    #pragma unroll
    for (int s = 0; s < NG; ++s) {
        const int j0 = 4 * t + 1024 * s;
        float rv[4];
        #pragma unroll
        for (int e = 0; e < 4; ++e) {
            const int j = j0 + e;
            float w = fminf((float)j * sc, (float)(SLEN - 1));
            int idx = (int)w;
            if (idx > SLEN - 2) idx = SLEN - 2;
            float tt  = w - (float)idx;
            float y0  = sy[idx];
            float y1  = sy[idx + 1];
            float m0  = sm[idx];
            float m1v = sm[idx + 1];
            float bb = (y1 - y0) - (2.0f * m0 + m1v) * (1.0f / 6.0f);
            float cc = 0.5f * m0;
            float dd = (m1v - m0) * (1.0f / 6.0f);
            rv[e] = y0 + tt * (bb + tt * (cc + tt * dd));
        }
        ((float4*)o)[t + BLK * s] = make_float4(rv[0], rv[1], rv[2], rv[3]);
    }
}

extern "C" void kernel_launch(void* const* d_in, const int* in_sizes, int n_in,
                              void* d_out, int out_size, void* d_ws, size_t ws_size,
                              hipStream_t stream) {
    const float* x     = (const float*)d_in[0];
    const float* scale = (const float*)d_in[1];
    const int*   mask  = (const int*)d_in[2];
    float*       out   = (float*)d_out;

    const int B     = in_sizes[1];            // 128
    const int total = in_sizes[0];            // B*C*S
    const int C     = total / (B * SLEN);     // 64
    const int nblk  = B * C;                  // 8192

    time_warp_kernel<<<nblk, BLK, 0, stream>>>(x, scale, mask, out, C);
}